// Round 9
// baseline (288.722 us; speedup 1.0000x reference)
//
#include <hip/hip_runtime.h>
#include <hip/hip_bf16.h>

#define TB 16
#define TS 1024
#define TQ 8
#define TL 512
#define TD 128

typedef __attribute__((ext_vector_type(8))) short bf16x8;
typedef __attribute__((ext_vector_type(4))) short short4v;
typedef __attribute__((ext_vector_type(4))) float f32x4;
typedef __attribute__((ext_vector_type(4))) float float4v;

__device__ __forceinline__ short f2bf(float f) {
    union { float fv; unsigned u; } v; v.fv = f;
    unsigned r = v.u + 0x7fffu + ((v.u >> 16) & 1u);
    return (short)(r >> 16);
}
__device__ __forceinline__ float bf2f(short s) {
    union { unsigned u; float f; } v; v.u = ((unsigned)(unsigned short)s) << 16;
    return v.f;
}

// ---------------- ws layout (bytes) ----------------
#define OFF_Q   0u                       // q bf16 [B][S][128] (pre-scaled) = 4 MiB
#define OFF_K   (4u << 20)               // k bf16 [B*Q][512][128]    = 16 MiB
#define OFF_V   (OFF_K + (16u << 20))    // v frag-interleaved        = 16 MiB
#define OFF_P0  (OFF_V + (16u << 20))    // qh=0 partial bf16 [B][S][128] = 4 MiB
#define OFF_W   (OFF_P0 + (4u << 20))    // 4x W^T bf16 [128][128]    = 128 KiB
// qh=1 partial lives in d_out (f32, 8 MiB) — combined in-place by comb_proj.

// ---------------- kernel 0: transpose weights to [e][k] bf16 ----------------
__global__ void prep_w(const float* __restrict__ Wq, const float* __restrict__ Wk,
                       const float* __restrict__ Wv, const float* __restrict__ Wo,
                       short* __restrict__ wt) {
    const float* srcs[4] = {Wq, Wk, Wv, Wo};
    const int m = blockIdx.x >> 3;
    const float* s = srcs[m];
    short* dst = wt + m * (TD * TD);
    const int off = (blockIdx.x & 7) * 2048;
    for (int i = threadIdx.x; i < 2048; i += 256) {
        int idx = off + i;
        int k = idx >> 7, e = idx & 127;       // coalesced read W[k][e]
        dst[e * TD + k] = f2bf(s[idx]);        // scattered 2B write (tiny matrix)
    }
}

// ---------------- kernel 1: fused q + k + v projections ----------------
// blocks [0,2048): kv rows of source; [2048,2560): q rows of target.
// q,K computed operand-SWAPPED (D lane holds 4 consecutive e) -> 8B stores.
// q is PRE-SCALED by 1/sqrt(128)*log2(e) so attn can exp2 raw scores.
// V computed in ORIGINAL order -> frag-interleaved layout:
//   elem(V[l][e]) at ((((l>>5)*8 + (e>>4))*4 + ((l>>3)&3))*16 + (e&15))*8 + (l&7)
__global__ __launch_bounds__(256) void proj_all(const float* __restrict__ target,
                                                const float* __restrict__ source,
                                                const short* __restrict__ wt,
                                                const float* __restrict__ biasq,
                                                const float* __restrict__ biask,
                                                const float* __restrict__ biasv,
                                                short* __restrict__ qb,
                                                short* __restrict__ kb,
                                                short* __restrict__ vf) {
    __shared__ short xt[32][136];              // +8 pad
    const int t = threadIdx.x;
    const int lane = t & 63, w = t >> 6;
    const int lane16 = lane & 15, g = lane >> 4;
    const bool iskv = blockIdx.x < 2048;
    const int r0 = (iskv ? blockIdx.x : (blockIdx.x - 2048)) * 32;
    const float* X = iskv ? source : target;

#pragma unroll
    for (int it = 0; it < 4; ++it) {
        int f4 = t + it * 256;
        int row = f4 >> 5, col = (f4 & 31) * 4;
        float4v x = *reinterpret_cast<const float4v*>(&X[(long)(r0 + row) * TD + col]);
        short4v s;
        s[0] = f2bf(x[0]); s[1] = f2bf(x[1]); s[2] = f2bf(x[2]); s[3] = f2bf(x[3]);
        *reinterpret_cast<short4v*>(&xt[row][col]) = s;
    }
    __syncthreads();

    const int n0 = w * 32;
    bf16x8 a[2][4];
#pragma unroll
    for (int mi = 0; mi < 2; ++mi)
#pragma unroll
        for (int kt = 0; kt < 4; ++kt)
            a[mi][kt] = *reinterpret_cast<const bf16x8*>(&xt[mi * 16 + lane16][kt * 32 + g * 8]);

    const f32x4 Z = {0.f, 0.f, 0.f, 0.f};
    if (iskv) {
        const short* Wtk = wt + 1 * TD * TD;
        const short* Wtv = wt + 2 * TD * TD;
        f32x4 ak[2][2] = {{Z, Z}, {Z, Z}};   // swapped: lane holds [e=g*4+reg][r=lane16]
        f32x4 av[2][2] = {{Z, Z}, {Z, Z}};   // original: lane holds [r=g*4+reg][e=lane16]
#pragma unroll
        for (int ni = 0; ni < 2; ++ni)
#pragma unroll
            for (int kt = 0; kt < 4; ++kt) {
                bf16x8 bkf = *reinterpret_cast<const bf16x8*>(
                    &Wtk[(n0 + ni * 16 + lane16) * TD + kt * 32 + g * 8]);
                bf16x8 bvf = *reinterpret_cast<const bf16x8*>(
                    &Wtv[(n0 + ni * 16 + lane16) * TD + kt * 32 + g * 8]);
#pragma unroll
                for (int mi = 0; mi < 2; ++mi) {
                    ak[mi][ni] = __builtin_amdgcn_mfma_f32_16x16x32_bf16(bkf, a[mi][kt], ak[mi][ni], 0, 0, 0);
                    av[mi][ni] = __builtin_amdgcn_mfma_f32_16x16x32_bf16(a[mi][kt], bvf, av[mi][ni], 0, 0, 0);
                }
            }
#pragma unroll
        for (int mi = 0; mi < 2; ++mi)
#pragma unroll
            for (int ni = 0; ni < 2; ++ni) {
                // K: row-major, 8B contiguous store of 4 consecutive e
                int e0 = n0 + ni * 16 + g * 4;
                float4v kb4 = *reinterpret_cast<const float4v*>(&biask[e0]);
                int row = r0 + mi * 16 + lane16;
                short4v ks;
#pragma unroll
                for (int reg = 0; reg < 4; ++reg) ks[reg] = f2bf(ak[mi][ni][reg] + kb4[reg]);
                *reinterpret_cast<short4v*>(&kb[(long)row * TD + e0]) = ks;
                // V: frag-interleaved 8B store (4 consecutive l for fixed e)
                int e = n0 + ni * 16 + lane16;
                float bbv = biasv[e];
                int row0 = r0 + mi * 16 + g * 4;
                int bq = row0 >> 9;
                int l = row0 & 511;
                int k32 = l >> 5, j8 = (l >> 3) & 3, jb = l & 7;
                long off = (long)bq * (TL * TD) +
                           ((((long)(k32 * 8 + (e >> 4)) * 4 + j8) * 16) + (e & 15)) * 8 + jb;
                short4v sv;
#pragma unroll
                for (int reg = 0; reg < 4; ++reg) sv[reg] = f2bf(av[mi][ni][reg] + bbv);
                *reinterpret_cast<short4v*>(&vf[off]) = sv;
            }
    } else {
        const short* Wtq = wt;
        const float CS = 0.08838834764831845f * 1.4426950408889634f; // 1/sqrt(128)*log2(e)
        f32x4 aq[2][2] = {{Z, Z}, {Z, Z}};   // swapped
#pragma unroll
        for (int ni = 0; ni < 2; ++ni)
#pragma unroll
            for (int kt = 0; kt < 4; ++kt) {
                bf16x8 bqf = *reinterpret_cast<const bf16x8*>(
                    &Wtq[(n0 + ni * 16 + lane16) * TD + kt * 32 + g * 8]);
#pragma unroll
                for (int mi = 0; mi < 2; ++mi)
                    aq[mi][ni] = __builtin_amdgcn_mfma_f32_16x16x32_bf16(bqf, a[mi][kt], aq[mi][ni], 0, 0, 0);
            }
#pragma unroll
        for (int mi = 0; mi < 2; ++mi)
#pragma unroll
            for (int ni = 0; ni < 2; ++ni) {
                int e0 = n0 + ni * 16 + g * 4;
                float4v qb4 = *reinterpret_cast<const float4v*>(&biasq[e0]);
                int row = r0 + mi * 16 + lane16;
                short4v qs;
#pragma unroll
                for (int reg = 0; reg < 4; ++reg) qs[reg] = f2bf((aq[mi][ni][reg] + qb4[reg]) * CS);
                *reinterpret_cast<short4v*>(&qb[(long)row * TD + e0]) = qs;
            }
    }
}

// ---------------- kernel 2: fused attention, (s x l)-split waves ----------------
// grid 1024: block = (b, 32 s-rows, q-half). 4 waves: wave w -> sg=w&1 (16
// s-rows), lh=w>>1 (256-l half). Scores S^T = mfma(K,Q) with sigma-permuted K
// rows -> held rows ARE the PV A-fragment (zero cross-lane movement).
// NO-MAX softmax (logits bounded; q pre-scaled so P = exp2(raw score)):
// per-wave sum + 2-way LDS combine, 1 barrier/q. Register budget: qf 16 +
// sacc 64 (transient) + pa 32 + o 32 ~= 150 total -> 3 waves/SIMD (round 8
// was ~184 -> 2/SIMD; the CSV VGPR_Count excludes accumulator regs).
// Partials: qh=0 -> bf16 po0; qh=1 -> f32 po1 (=d_out).
__global__ __launch_bounds__(256, 2) void attn_k(const short* __restrict__ qb,
                                                 const short* __restrict__ kb,
                                                 const short* __restrict__ vf,
                                                 short* __restrict__ po0,
                                                 float* __restrict__ po1) {
    __shared__ float cmb[2][2][2][16];         // [q&1][lh][sg][s-col] sums, 512 B
    __shared__ float red[2][8][4][16][4];      // [sg][et][g][s-col][reg] = 16 KB
    const int t = threadIdx.x;
    const int lane = t & 63, w = t >> 6;
    const int lane16 = lane & 15, g = lane >> 4;
    const int sg = w & 1, lh = w >> 1;

    // XCD remap: each XCD owns 2 b's -> its K+V (4MB) fits the private L2.
    int idx = blockIdx.x;
    int xcd = idx & 7, slot = idx >> 3;        // slot in [0,128)
    const int b = xcd * 2 + (slot >> 6);
    const int rem = slot & 63;
    const int qh = rem >> 5;
    const int s0 = (rem & 31) * 32;

    // Q B-fragments for this wave's 16 s-rows only
    bf16x8 qf[4];
    {
        const short* qrow = qb + (long)(b * TS + s0 + sg * 16 + lane16) * TD;
#pragma unroll
        for (int kt = 0; kt < 4; ++kt)
            qf[kt] = *reinterpret_cast<const bf16x8*>(qrow + kt * 32 + g * 8);
    }

    const f32x4 Z = {0.f, 0.f, 0.f, 0.f};
    f32x4 o[8];
#pragma unroll
    for (int et = 0; et < 8; ++et) o[et] = Z;

    const int arow = 8 * (lane16 >> 2) + (lane16 & 3);   // sigma(lane16)

    for (int qi = qh * 4; qi < qh * 4 + 4; ++qi) {
        const long kvb = (long)(b * TQ + qi) * (TL * TD);
        const short* Kw = kb + kvb + (long)(lh * 256) * TD;

        // ---- scores S^T (K as A, Q as B) over this wave's 256-l half ----
        f32x4 sacc[16];
#pragma unroll
        for (int lt = 0; lt < 16; ++lt) sacc[lt] = Z;
#pragma unroll
        for (int lt = 0; lt < 16; ++lt) {
            const short* krow = Kw + (long)(32 * (lt >> 1) + 4 * (lt & 1) + arow) * TD;
            bf16x8 ka[4];
#pragma unroll
            for (int kt = 0; kt < 4; ++kt)
                ka[kt] = *reinterpret_cast<const bf16x8*>(krow + kt * 32 + g * 8);
#pragma unroll
            for (int kt = 0; kt < 4; ++kt)
                sacc[lt] = __builtin_amdgcn_mfma_f32_16x16x32_bf16(ka[kt], qf[kt], sacc[lt], 0, 0, 0);
        }

        // ---- no-max softmax: exp2 in place, sum, 2-way cross-wave combine ----
        float sum = 0.f;
#pragma unroll
        for (int lt = 0; lt < 16; ++lt)
#pragma unroll
            for (int r = 0; r < 4; ++r) {
                float e = exp2f(sacc[lt][r]);
                sacc[lt][r] = e;
                sum += e;
            }
        sum += __shfl_xor(sum, 16);
        sum += __shfl_xor(sum, 32);
        if (lane < 16) cmb[qi & 1][lh][sg][lane16] = sum;
        __syncthreads();
        float Fs = 1.f / (cmb[qi & 1][0][sg][lane16] + cmb[qi & 1][1][sg][lane16]);

        // ---- pack normalized P into PV A-fragments (zero cross-lane moves) ----
        bf16x8 pa[8];
#pragma unroll
        for (int kt = 0; kt < 8; ++kt) {
#pragma unroll
            for (int j = 0; j < 4; ++j)
                pa[kt][j] = f2bf(sacc[2 * kt][j] * Fs);
#pragma unroll
            for (int j = 0; j < 4; ++j)
                pa[kt][4 + j] = f2bf(sacc[2 * kt + 1][j] * Fs);
        }

        // ---- PV over this wave's 256-l half ----
#pragma unroll
        for (int kt = 0; kt < 8; ++kt) {
            const short* vbase = vf + kvb + ((long)(lh * 8 + kt) * 4096) + g * 128 + lane16 * 8;
#pragma unroll
            for (int et = 0; et < 8; ++et) {
                bf16x8 vb = *reinterpret_cast<const bf16x8*>(vbase + et * 512);
                o[et] = __builtin_amdgcn_mfma_f32_16x16x32_bf16(pa[kt], vb, o[et], 0, 0, 0);
            }
        }
    }

    // ---- combine lh pairs: lh=1 -> LDS; lh=0 adds and stores partial ----
    if (lh == 1) {
#pragma unroll
        for (int et = 0; et < 8; ++et)
            *reinterpret_cast<f32x4*>(&red[sg][et][g][lane16][0]) = o[et];
    }
    __syncthreads();
    if (lh == 0) {
#pragma unroll
        for (int et = 0; et < 8; ++et) {
            o[et] += *reinterpret_cast<f32x4*>(&red[sg][et][g][lane16][0]);
#pragma unroll
            for (int reg = 0; reg < 4; ++reg) {
                int s = s0 + sg * 16 + g * 4 + reg;
                long addr = (long)(b * TS + s) * TD + et * 16 + lane16;
                if (qh == 0) po0[addr] = f2bf(o[et][reg]);
                else         po1[addr] = o[et][reg];
            }
        }
    }
}

// ---------------- kernel 3: combine partials + output projection ----------------
// att = po0(bf16) + po1(f32, in d_out); out = att @ Wo^T + bo (in-place d_out).
__global__ __launch_bounds__(256) void comb_proj(const short* __restrict__ po0,
                                                 const short* __restrict__ Wt,
                                                 const float* __restrict__ bias,
                                                 float* __restrict__ out) {
    const int t = threadIdx.x;
    const int lane = t & 63, w = t >> 6;
    const int lane16 = lane & 15, g = lane >> 4;
    const int r0 = blockIdx.x * 32;
    const int n0 = w * 32;

    // att fragments (used as MFMA B): 8 consecutive e for row lane16
    bf16x8 a[2][4];
#pragma unroll
    for (int mi = 0; mi < 2; ++mi)
#pragma unroll
        for (int kt = 0; kt < 4; ++kt) {
            long base = (long)(r0 + mi * 16 + lane16) * TD + kt * 32 + g * 8;
            float4v x0 = *reinterpret_cast<const float4v*>(&out[base]);
            float4v x1 = *reinterpret_cast<const float4v*>(&out[base + 4]);
            bf16x8 p0 = *reinterpret_cast<const bf16x8*>(&po0[base]);
            bf16x8 af;
#pragma unroll
            for (int j = 0; j < 4; ++j) af[j] = f2bf(x0[j] + bf2f(p0[j]));
#pragma unroll
            for (int j = 0; j < 4; ++j) af[4 + j] = f2bf(x1[j] + bf2f(p0[4 + j]));
            a[mi][kt] = af;
        }
    __syncthreads();   // all reads of out (=po1) complete before in-place writes

    const f32x4 Z = {0.f, 0.f, 0.f, 0.f};
    f32x4 acc[2][2] = {{Z, Z}, {Z, Z}};      // swapped: lane holds 4 consecutive e'
#pragma unroll
    for (int ni = 0; ni < 2; ++ni)
#pragma unroll
        for (int kt = 0; kt < 4; ++kt) {
            bf16x8 wf = *reinterpret_cast<const bf16x8*>(
                &Wt[(n0 + ni * 16 + lane16) * TD + kt * 32 + g * 8]);
#pragma unroll
            for (int mi = 0; mi < 2; ++mi)
                acc[mi][ni] = __builtin_amdgcn_mfma_f32_16x16x32_bf16(wf, a[mi][kt], acc[mi][ni], 0, 0, 0);
        }

#pragma unroll
    for (int mi = 0; mi < 2; ++mi)
#pragma unroll
        for (int ni = 0; ni < 2; ++ni) {
            int e0 = n0 + ni * 16 + g * 4;
            float4v b4 = *reinterpret_cast<const float4v*>(&bias[e0]);
            int row = r0 + mi * 16 + lane16;
            f32x4 res;
#pragma unroll
            for (int reg = 0; reg < 4; ++reg) res[reg] = acc[mi][ni][reg] + b4[reg];
            *reinterpret_cast<f32x4*>(&out[(long)row * TD + e0]) = res;
        }
}

extern "C" void kernel_launch(void* const* d_in, const int* in_sizes, int n_in,
                              void* d_out, int out_size, void* d_ws, size_t ws_size,
                              hipStream_t stream) {
    (void)in_sizes; (void)n_in; (void)out_size; (void)ws_size;
    const float* target = (const float*)d_in[0];
    const float* source = (const float*)d_in[1];
    const float* Wq = (const float*)d_in[2];
    const float* bq = (const float*)d_in[3];
    const float* Wk = (const float*)d_in[4];
    const float* bk = (const float*)d_in[5];
    const float* Wv = (const float*)d_in[6];
    const float* bv = (const float*)d_in[7];
    const float* Wo = (const float*)d_in[8];
    const float* bo = (const float*)d_in[9];

    char* ws = (char*)d_ws;
    short* qb  = (short*)(ws + OFF_Q);
    short* kb  = (short*)(ws + OFF_K);
    short* vf  = (short*)(ws + OFF_V);
    short* po0 = (short*)(ws + OFF_P0);
    short* wt  = (short*)(ws + OFF_W);
    float* out = (float*)d_out;

    prep_w<<<32, 256, 0, stream>>>(Wq, Wk, Wv, Wo, wt);
    proj_all<<<2560, 256, 0, stream>>>(target, source, wt, bq, bk, bv, qb, kb, vf);
    attn_k<<<1024, 256, 0, stream>>>(qb, kb, vf, po0, out);
    comb_proj<<<512, 256, 0, stream>>>(po0, wt + 3 * TD * TD, bo, out);
}

// Round 11
// 220.652 us; speedup vs baseline: 1.3085x; 1.3085x over previous
//
#include <hip/hip_runtime.h>
#include <hip/hip_bf16.h>

#define TB 16
#define TS 1024
#define TQ 8
#define TL 512
#define TD 128

typedef __attribute__((ext_vector_type(8))) short bf16x8;
typedef __attribute__((ext_vector_type(4))) short short4v;
typedef __attribute__((ext_vector_type(4))) float f32x4;
typedef __attribute__((ext_vector_type(4))) float float4v;

__device__ __forceinline__ short f2bf(float f) {
    union { float fv; unsigned u; } v; v.fv = f;
    unsigned r = v.u + 0x7fffu + ((v.u >> 16) & 1u);
    return (short)(r >> 16);
}
__device__ __forceinline__ float bf2f(short s) {
    union { unsigned u; float f; } v; v.u = ((unsigned)(unsigned short)s) << 16;
    return v.f;
}

// ---------------- ws layout (bytes) ----------------
#define OFF_Q   0u                       // q bf16 [B][S][128] (pre-scaled) = 4 MiB
#define OFF_K   (4u << 20)               // k bf16 [B*Q][512][128]    = 16 MiB
#define OFF_V   (OFF_K + (16u << 20))    // v frag-interleaved        = 16 MiB
#define OFF_P0  (OFF_V + (16u << 20))    // qh=0 partial bf16 [B][S][128] = 4 MiB
#define OFF_W   (OFF_P0 + (4u << 20))    // 4x W^T bf16 [128][128]    = 128 KiB
// qh=1 partial lives in d_out (f32, 8 MiB) — combined in-place by comb_proj.

// ---------------- kernel 0: transpose weights to [e][k] bf16 ----------------
__global__ void prep_w(const float* __restrict__ Wq, const float* __restrict__ Wk,
                       const float* __restrict__ Wv, const float* __restrict__ Wo,
                       short* __restrict__ wt) {
    const float* srcs[4] = {Wq, Wk, Wv, Wo};
    const int m = blockIdx.x >> 3;
    const float* s = srcs[m];
    short* dst = wt + m * (TD * TD);
    const int off = (blockIdx.x & 7) * 2048;
    for (int i = threadIdx.x; i < 2048; i += 256) {
        int idx = off + i;
        int k = idx >> 7, e = idx & 127;       // coalesced read W[k][e]
        dst[e * TD + k] = f2bf(s[idx]);        // scattered 2B write (tiny matrix)
    }
}

// ---------------- kernel 1: fused q + k + v projections ----------------
// blocks [0,2048): kv rows of source; [2048,2560): q rows of target.
// q,K computed operand-SWAPPED (D lane holds 4 consecutive e) -> 8B stores.
// q is PRE-SCALED by 1/sqrt(128)*log2(e) so attn can exp2 raw scores (no-max
// softmax: logits tiny, softmax shift-invariant; HW-validated round 9).
// V computed in ORIGINAL order -> frag-interleaved layout:
//   elem(V[l][e]) at ((((l>>5)*8 + (e>>4))*4 + ((l>>3)&3))*16 + (e&15))*8 + (l&7)
__global__ __launch_bounds__(256) void proj_all(const float* __restrict__ target,
                                                const float* __restrict__ source,
                                                const short* __restrict__ wt,
                                                const float* __restrict__ biasq,
                                                const float* __restrict__ biask,
                                                const float* __restrict__ biasv,
                                                short* __restrict__ qb,
                                                short* __restrict__ kb,
                                                short* __restrict__ vf) {
    __shared__ short xt[32][136];              // +8 pad
    const int t = threadIdx.x;
    const int lane = t & 63, w = t >> 6;
    const int lane16 = lane & 15, g = lane >> 4;
    const bool iskv = blockIdx.x < 2048;
    const int r0 = (iskv ? blockIdx.x : (blockIdx.x - 2048)) * 32;
    const float* X = iskv ? source : target;

#pragma unroll
    for (int it = 0; it < 4; ++it) {
        int f4 = t + it * 256;
        int row = f4 >> 5, col = (f4 & 31) * 4;
        float4v x = *reinterpret_cast<const float4v*>(&X[(long)(r0 + row) * TD + col]);
        short4v s;
        s[0] = f2bf(x[0]); s[1] = f2bf(x[1]); s[2] = f2bf(x[2]); s[3] = f2bf(x[3]);
        *reinterpret_cast<short4v*>(&xt[row][col]) = s;
    }
    __syncthreads();

    const int n0 = w * 32;
    bf16x8 a[2][4];
#pragma unroll
    for (int mi = 0; mi < 2; ++mi)
#pragma unroll
        for (int kt = 0; kt < 4; ++kt)
            a[mi][kt] = *reinterpret_cast<const bf16x8*>(&xt[mi * 16 + lane16][kt * 32 + g * 8]);

    const f32x4 Z = {0.f, 0.f, 0.f, 0.f};
    if (iskv) {
        const short* Wtk = wt + 1 * TD * TD;
        const short* Wtv = wt + 2 * TD * TD;
        f32x4 ak[2][2] = {{Z, Z}, {Z, Z}};   // swapped: lane holds [e=g*4+reg][r=lane16]
        f32x4 av[2][2] = {{Z, Z}, {Z, Z}};   // original: lane holds [r=g*4+reg][e=lane16]
#pragma unroll
        for (int ni = 0; ni < 2; ++ni)
#pragma unroll
            for (int kt = 0; kt < 4; ++kt) {
                bf16x8 bkf = *reinterpret_cast<const bf16x8*>(
                    &Wtk[(n0 + ni * 16 + lane16) * TD + kt * 32 + g * 8]);
                bf16x8 bvf = *reinterpret_cast<const bf16x8*>(
                    &Wtv[(n0 + ni * 16 + lane16) * TD + kt * 32 + g * 8]);
#pragma unroll
                for (int mi = 0; mi < 2; ++mi) {
                    ak[mi][ni] = __builtin_amdgcn_mfma_f32_16x16x32_bf16(bkf, a[mi][kt], ak[mi][ni], 0, 0, 0);
                    av[mi][ni] = __builtin_amdgcn_mfma_f32_16x16x32_bf16(a[mi][kt], bvf, av[mi][ni], 0, 0, 0);
                }
            }
#pragma unroll
        for (int mi = 0; mi < 2; ++mi)
#pragma unroll
            for (int ni = 0; ni < 2; ++ni) {
                // K: row-major, 8B contiguous store of 4 consecutive e
                int e0 = n0 + ni * 16 + g * 4;
                float4v kb4 = *reinterpret_cast<const float4v*>(&biask[e0]);
                int row = r0 + mi * 16 + lane16;
                short4v ks;
#pragma unroll
                for (int reg = 0; reg < 4; ++reg) ks[reg] = f2bf(ak[mi][ni][reg] + kb4[reg]);
                *reinterpret_cast<short4v*>(&kb[(long)row * TD + e0]) = ks;
                // V: frag-interleaved 8B store (4 consecutive l for fixed e)
                int e = n0 + ni * 16 + lane16;
                float bbv = biasv[e];
                int row0 = r0 + mi * 16 + g * 4;
                int bq = row0 >> 9;
                int l = row0 & 511;
                int k32 = l >> 5, j8 = (l >> 3) & 3, jb = l & 7;
                long off = (long)bq * (TL * TD) +
                           ((((long)(k32 * 8 + (e >> 4)) * 4 + j8) * 16) + (e & 15)) * 8 + jb;
                short4v sv;
#pragma unroll
                for (int reg = 0; reg < 4; ++reg) sv[reg] = f2bf(av[mi][ni][reg] + bbv);
                *reinterpret_cast<short4v*>(&vf[off]) = sv;
            }
    } else {
        const short* Wtq = wt;
        const float CS = 0.08838834764831845f * 1.4426950408889634f; // 1/sqrt(128)*log2(e)
        f32x4 aq[2][2] = {{Z, Z}, {Z, Z}};   // swapped
#pragma unroll
        for (int ni = 0; ni < 2; ++ni)
#pragma unroll
            for (int kt = 0; kt < 4; ++kt) {
                bf16x8 bqf = *reinterpret_cast<const bf16x8*>(
                    &Wtq[(n0 + ni * 16 + lane16) * TD + kt * 32 + g * 8]);
#pragma unroll
                for (int mi = 0; mi < 2; ++mi)
                    aq[mi][ni] = __builtin_amdgcn_mfma_f32_16x16x32_bf16(bqf, a[mi][kt], aq[mi][ni], 0, 0, 0);
            }
#pragma unroll
        for (int mi = 0; mi < 2; ++mi)
#pragma unroll
            for (int ni = 0; ni < 2; ++ni) {
                int e0 = n0 + ni * 16 + g * 4;
                float4v qb4 = *reinterpret_cast<const float4v*>(&biasq[e0]);
                int row = r0 + mi * 16 + lane16;
                short4v qs;
#pragma unroll
                for (int reg = 0; reg < 4; ++reg) qs[reg] = f2bf((aq[mi][ni][reg] + qb4[reg]) * CS);
                *reinterpret_cast<short4v*>(&qb[(long)row * TD + e0]) = qs;
            }
    }
}

// ---------------- kernel 2: fused attention (round-8 partition) ----------------
// grid 1024: block = (b, 32 s-rows, q-half). 4 waves; wave w owns l-slice
// [w*128,(w+1)*128) for BOTH scores and PV (32 K-loads + 32 V-loads per q,
// every K row / V elem read once per block -- round 9's (s x l) split doubled
// this and regressed). Scores S^T = mfma(K,Q) with sigma-permuted K rows ->
// held rows ARE the PV A-fragment (zero cross-lane movement).
// NO-MAX softmax (q pre-scaled; P = exp2(raw score)), sum-only combine,
// 1 barrier/q. P->bf16 pack via v_cvt_pk_bf16_f32 (2 f32/instr).
// Partials: qh=0 -> bf16 po0; qh=1 -> f32 po1 (=d_out).
// launch_bounds (256,2): (256,4) caps VGPR at 128 -> catastrophic spill (r5).
__global__ __launch_bounds__(256, 2) void attn_k(const short* __restrict__ qb,
                                                 const short* __restrict__ kb,
                                                 const short* __restrict__ vf,
                                                 short* __restrict__ po0,
                                                 float* __restrict__ po1) {
    __shared__ float cmb[2][4][2][16];         // [q&1][wave][sg][s-col] sums, 1KB
    __shared__ float red[2][2][8][4][16][4];   // 32KB
    const int t = threadIdx.x;
    const int lane = t & 63, w = t >> 6;
    const int lane16 = lane & 15, g = lane >> 4;

    // XCD remap: each XCD owns 2 b's -> its K+V (4MB) fits the private L2.
    int idx = blockIdx.x;
    int xcd = idx & 7, slot = idx >> 3;        // slot in [0,128)
    const int b = xcd * 2 + (slot >> 6);
    const int rem = slot & 63;
    const int qh = rem >> 5;
    const int s0 = (rem & 31) * 32;

    bf16x8 qf[2][4];
#pragma unroll
    for (int sg = 0; sg < 2; ++sg) {
        const short* qrow = qb + (long)(b * TS + s0 + sg * 16 + lane16) * TD;
#pragma unroll
        for (int kt = 0; kt < 4; ++kt)
            qf[sg][kt] = *reinterpret_cast<const bf16x8*>(qrow + kt * 32 + g * 8);
    }

    const f32x4 Z = {0.f, 0.f, 0.f, 0.f};
    f32x4 o[2][8];
#pragma unroll
    for (int sg = 0; sg < 2; ++sg)
#pragma unroll
        for (int et = 0; et < 8; ++et) o[sg][et] = Z;

    const int arow = 8 * (lane16 >> 2) + (lane16 & 3);   // sigma(lane16)

    for (int qi = qh * 4; qi < qh * 4 + 4; ++qi) {
        const long kvb = (long)(b * TQ + qi) * (TL * TD);
        const short* Kw = kb + kvb + (long)(w * 128) * TD;

        // ---- scores S^T (K as A, Q as B), sigma-permuted rows ----
        f32x4 sacc[2][8];
#pragma unroll
        for (int sg = 0; sg < 2; ++sg)
#pragma unroll
            for (int lt = 0; lt < 8; ++lt) sacc[sg][lt] = Z;
#pragma unroll
        for (int lt = 0; lt < 8; ++lt) {
            const short* krow = Kw + (long)(32 * (lt >> 1) + 4 * (lt & 1) + arow) * TD;
            bf16x8 ka[4];
#pragma unroll
            for (int kt = 0; kt < 4; ++kt)
                ka[kt] = *reinterpret_cast<const bf16x8*>(krow + kt * 32 + g * 8);
#pragma unroll
            for (int kt = 0; kt < 4; ++kt) {
                sacc[0][lt] = __builtin_amdgcn_mfma_f32_16x16x32_bf16(ka[kt], qf[0][kt], sacc[0][lt], 0, 0, 0);
                sacc[1][lt] = __builtin_amdgcn_mfma_f32_16x16x32_bf16(ka[kt], qf[1][kt], sacc[1][lt], 0, 0, 0);
            }
        }

        // ---- no-max softmax: exp2 in place, per-wave sums -> LDS combine ----
#pragma unroll
        for (int sg = 0; sg < 2; ++sg) {
            float sum = 0.f;
#pragma unroll
            for (int lt = 0; lt < 8; ++lt)
#pragma unroll
                for (int r = 0; r < 4; ++r) {
                    float e = exp2f(sacc[sg][lt][r]);
                    sacc[sg][lt][r] = e;
                    sum += e;
                }
            sum += __shfl_xor(sum, 16);
            sum += __shfl_xor(sum, 32);
            if (lane < 16) cmb[qi & 1][w][sg][lane16] = sum;
        }
        __syncthreads();
        float Fs[2];
#pragma unroll
        for (int sg = 0; sg < 2; ++sg)
            Fs[sg] = 1.f / (cmb[qi & 1][0][sg][lane16] + cmb[qi & 1][1][sg][lane16]
                          + cmb[qi & 1][2][sg][lane16] + cmb[qi & 1][3][sg][lane16]);

        // ---- pack normalized P into PV A-fragments via v_cvt_pk_bf16_f32 ----
        bf16x8 pa[2][4];
#pragma unroll
        for (int sg = 0; sg < 2; ++sg)
#pragma unroll
            for (int kt = 0; kt < 4; ++kt) {
                union { unsigned u[4]; bf16x8 v; } pk;
#pragma unroll
                for (int h = 0; h < 2; ++h) {
                    float x0 = sacc[sg][2 * kt + h][0] * Fs[sg];
                    float x1 = sacc[sg][2 * kt + h][1] * Fs[sg];
                    float x2 = sacc[sg][2 * kt + h][2] * Fs[sg];
                    float x3 = sacc[sg][2 * kt + h][3] * Fs[sg];
                    asm("v_cvt_pk_bf16_f32 %0, %1, %2" : "=v"(pk.u[2 * h]) : "v"(x0), "v"(x1));
                    asm("v_cvt_pk_bf16_f32 %0, %1, %2" : "=v"(pk.u[2 * h + 1]) : "v"(x2), "v"(x3));
                }
                pa[sg][kt] = pk.v;
            }

        // ---- PV over this wave's l-slice ----
#pragma unroll
        for (int kt = 0; kt < 4; ++kt) {
            const short* vbase = vf + kvb + ((long)(w * 4 + kt) * 4096) + g * 128 + lane16 * 8;
#pragma unroll
            for (int et = 0; et < 8; ++et) {
                bf16x8 vb = *reinterpret_cast<const bf16x8*>(vbase + et * 512);
                o[0][et] = __builtin_amdgcn_mfma_f32_16x16x32_bf16(pa[0][kt], vb, o[0][et], 0, 0, 0);
                o[1][et] = __builtin_amdgcn_mfma_f32_16x16x32_bf16(pa[1][kt], vb, o[1][et], 0, 0, 0);
            }
        }
    }

    // ---- cross-wave o reduction -> w0 stores partial ----
    if (w >= 2) {
#pragma unroll
        for (int sg = 0; sg < 2; ++sg)
#pragma unroll
            for (int et = 0; et < 8; ++et)
                *reinterpret_cast<f32x4*>(&red[w - 2][sg][et][g][lane16][0]) = o[sg][et];
    }
    __syncthreads();
    if (w < 2) {
#pragma unroll
        for (int sg = 0; sg < 2; ++sg)
#pragma unroll
            for (int et = 0; et < 8; ++et)
                o[sg][et] += *reinterpret_cast<f32x4*>(&red[w][sg][et][g][lane16][0]);
    }
    __syncthreads();
    if (w == 1) {
#pragma unroll
        for (int sg = 0; sg < 2; ++sg)
#pragma unroll
            for (int et = 0; et < 8; ++et)
                *reinterpret_cast<f32x4*>(&red[0][sg][et][g][lane16][0]) = o[sg][et];
    }
    __syncthreads();
    if (w == 0) {
#pragma unroll
        for (int sg = 0; sg < 2; ++sg)
#pragma unroll
            for (int et = 0; et < 8; ++et) {
                o[sg][et] += *reinterpret_cast<f32x4*>(&red[0][sg][et][g][lane16][0]);
#pragma unroll
                for (int reg = 0; reg < 4; ++reg) {
                    int s = s0 + sg * 16 + g * 4 + reg;
                    long addr = (long)(b * TS + s) * TD + et * 16 + lane16;
                    if (qh == 0) po0[addr] = f2bf(o[sg][et][reg]);
                    else         po1[addr] = o[sg][et][reg];
                }
            }
    }
}

// ---------------- kernel 3: combine partials + output projection ----------------
// att = po0(bf16) + po1(f32, in d_out); out = att @ Wo^T + bo (in-place d_out).
__global__ __launch_bounds__(256) void comb_proj(const short* __restrict__ po0,
                                                 const short* __restrict__ Wt,
                                                 const float* __restrict__ bias,
                                                 float* __restrict__ out) {
    const int t = threadIdx.x;
    const int lane = t & 63, w = t >> 6;
    const int lane16 = lane & 15, g = lane >> 4;
    const int r0 = blockIdx.x * 32;
    const int n0 = w * 32;

    // att fragments (used as MFMA B): 8 consecutive e for row lane16
    bf16x8 a[2][4];
#pragma unroll
    for (int mi = 0; mi < 2; ++mi)
#pragma unroll
        for (int kt = 0; kt < 4; ++kt) {
            long base = (long)(r0 + mi * 16 + lane16) * TD + kt * 32 + g * 8;
            float4v x0 = *reinterpret_cast<const float4v*>(&out[base]);
            float4v x1 = *reinterpret_cast<const float4v*>(&out[base + 4]);
            bf16x8 p0 = *reinterpret_cast<const bf16x8*>(&po0[base]);
            bf16x8 af;
#pragma unroll
            for (int j = 0; j < 4; ++j) af[j] = f2bf(x0[j] + bf2f(p0[j]));
#pragma unroll
            for (int j = 0; j < 4; ++j) af[4 + j] = f2bf(x1[j] + bf2f(p0[4 + j]));
            a[mi][kt] = af;
        }
    __syncthreads();   // all reads of out (=po1) complete before in-place writes

    const f32x4 Z = {0.f, 0.f, 0.f, 0.f};
    f32x4 acc[2][2] = {{Z, Z}, {Z, Z}};      // swapped: lane holds 4 consecutive e'
#pragma unroll
    for (int ni = 0; ni < 2; ++ni)
#pragma unroll
        for (int kt = 0; kt < 4; ++kt) {
            bf16x8 wf = *reinterpret_cast<const bf16x8*>(
                &Wt[(n0 + ni * 16 + lane16) * TD + kt * 32 + g * 8]);
#pragma unroll
            for (int mi = 0; mi < 2; ++mi)
                acc[mi][ni] = __builtin_amdgcn_mfma_f32_16x16x32_bf16(wf, a[mi][kt], acc[mi][ni], 0, 0, 0);
        }

#pragma unroll
    for (int mi = 0; mi < 2; ++mi)
#pragma unroll
        for (int ni = 0; ni < 2; ++ni) {
            int e0 = n0 + ni * 16 + g * 4;
            float4v b4 = *reinterpret_cast<const float4v*>(&bias[e0]);
            int row = r0 + mi * 16 + lane16;
            f32x4 res;
#pragma unroll
            for (int reg = 0; reg < 4; ++reg) res[reg] = acc[mi][ni][reg] + b4[reg];
            *reinterpret_cast<f32x4*>(&out[(long)row * TD + e0]) = res;
        }
}

extern "C" void kernel_launch(void* const* d_in, const int* in_sizes, int n_in,
                              void* d_out, int out_size, void* d_ws, size_t ws_size,
                              hipStream_t stream) {
    (void)in_sizes; (void)n_in; (void)out_size; (void)ws_size;
    const float* target = (const float*)d_in[0];
    const float* source = (const float*)d_in[1];
    const float* Wq = (const float*)d_in[2];
    const float* bq = (const float*)d_in[3];
    const float* Wk = (const float*)d_in[4];
    const float* bk = (const float*)d_in[5];
    const float* Wv = (const float*)d_in[6];
    const float* bv = (const float*)d_in[7];
    const float* Wo = (const float*)d_in[8];
    const float* bo = (const float*)d_in[9];

    char* ws = (char*)d_ws;
    short* qb  = (short*)(ws + OFF_Q);
    short* kb  = (short*)(ws + OFF_K);
    short* vf  = (short*)(ws + OFF_V);
    short* po0 = (short*)(ws + OFF_P0);
    short* wt  = (short*)(ws + OFF_W);
    float* out = (float*)d_out;

    prep_w<<<32, 256, 0, stream>>>(Wq, Wk, Wv, Wo, wt);
    proj_all<<<2560, 256, 0, stream>>>(target, source, wt, bq, bk, bv, qb, kb, vf);
    attn_k<<<1024, 256, 0, stream>>>(qb, kb, vf, po0, out);
    comb_proj<<<512, 256, 0, stream>>>(po0, wt + 3 * TD * TD, bo, out);
}